// Round 9
// baseline (2014.284 us; speedup 1.0000x reference)
//
#include <hip/hip_runtime.h>
#include <math.h>

// Problem constants (B, D_IN, H, NZ, NC)
#define BN    32768
#define DIN   768
#define HN    2048
#define NZ    128
#define NCN   1024

typedef __attribute__((ext_vector_type(8))) short s16x8;
typedef __attribute__((ext_vector_type(4))) float f32x4;
typedef unsigned short u16;

#define MFMA16(a,b,c) __builtin_amdgcn_mfma_f32_16x16x32_bf16(a,b,c,0,0,0)

__device__ __forceinline__ u16 bf16_rne(float x){
  unsigned u = __float_as_uint(x);
  unsigned r = (u + 0x7FFFu + ((u >> 16) & 1u)) >> 16;
  return (u16)r;
}
__device__ __forceinline__ float bf16_tof(u16 h){
  return __uint_as_float(((unsigned)h) << 16);
}
__device__ __forceinline__ void split3(float x, u16& h, u16& m, u16& l){
  h = bf16_rne(x);
  float r1 = x - bf16_tof(h);
  m = bf16_rne(r1);
  float r2 = r1 - bf16_tof(m);
  l = bf16_rne(r2);
}

__device__ __forceinline__ void gload16(const void* gsrc, void* lds){
  __builtin_amdgcn_global_load_lds(
      (const __attribute__((address_space(1))) unsigned int*)gsrc,
      (__attribute__((address_space(3))) unsigned int*)lds, 16, 0, 0);
}

// ---------------- K0: init (u=1, histograms=0) ----------------
__global__ __launch_bounds__(1024) void k0_init(float* u, int* hraw, int* hclu){
  const int k = threadIdx.x;
  u[k] = 1.0f;
  hraw[k] = 0;
  hclu[k] = 0;
}

// ---------------- Convert: elementwise 3-way bf16 split ----------------
__global__ __launch_bounds__(256) void c_split(
    const float* __restrict__ in, u16* __restrict__ oh, u16* __restrict__ om,
    u16* __restrict__ ol, int n4)
{
  const int i = blockIdx.x*256 + threadIdx.x;
  if (i >= n4) return;
  const f32x4 v = *(const f32x4*)&in[(size_t)i*4];
  ushort4 h4, m4, l4;
  split3(v[0], h4.x, m4.x, l4.x);
  split3(v[1], h4.y, m4.y, l4.y);
  split3(v[2], h4.z, m4.z, l4.z);
  split3(v[3], h4.w, m4.w, l4.w);
  *(ushort4*)&oh[(size_t)i*4] = h4;
  *(ushort4*)&om[(size_t)i*4] = m4;
  *(ushort4*)&ol[(size_t)i*4] = l4;
}

// ---------------- Convert: transpose + 3-way bf16 split ----------------
__global__ __launch_bounds__(256) void c_tsplit(
    const float* __restrict__ in, int R, int C,
    u16* __restrict__ oh, u16* __restrict__ om, u16* __restrict__ ol)
{
  __shared__ float L[64][65];
  const int t = threadIdx.x;
  const int bi = blockIdx.x, bj = blockIdx.y;
  #pragma unroll
  for (int m=0;m<4;++m){
    int flat = t + 256*m;
    int r = flat >> 4, c4 = (flat & 15) << 2;
    const float4 v = *(const float4*)&in[(size_t)(bi*64 + r)*C + bj*64 + c4];
    L[r][c4+0] = v.x; L[r][c4+1] = v.y; L[r][c4+2] = v.z; L[r][c4+3] = v.w;
  }
  __syncthreads();
  #pragma unroll
  for (int m=0;m<4;++m){
    int flat = t + 256*m;
    int oc = flat >> 4, k4 = (flat & 15) << 2;
    ushort4 h4, m4, l4;
    split3(L[k4+0][oc], h4.x, m4.x, l4.x);
    split3(L[k4+1][oc], h4.y, m4.y, l4.y);
    split3(L[k4+2][oc], h4.z, m4.z, l4.z);
    split3(L[k4+3][oc], h4.w, m4.w, l4.w);
    size_t off = (size_t)(bj*64 + oc)*R + bi*64 + k4;
    *(ushort4*)&oh[off] = h4;
    *(ushort4*)&om[off] = m4;
    *(ushort4*)&ol[off] = l4;
  }
}

// ---------------- Convert: row sum-of-squares, rows of 128 ----------------
__global__ __launch_bounds__(256) void c_norm(
    const float* __restrict__ in, float* __restrict__ out)
{
  const int w = threadIdx.x >> 6, l = threadIdx.x & 63;
  const int row = blockIdx.x*4 + w;
  const float2 v = *(const float2*)&in[(size_t)row*128 + l*2];
  float s = v.x*v.x + v.y*v.y;
  #pragma unroll
  for (int off=32; off; off>>=1) s += __shfl_xor(s, off, 64);
  if (l == 0) out[row] = s;
}

// ---------------- K1: fused MFMA backbone fv = relu(X@W1+b1)@W2 + b2 ----------------
// R6 structure + phase-A A-fragments read DIRECTLY from global (X pre-split in
// fragment layout) -> X LDS staging and A ds_reads eliminated (k1 was
// LDS-BW-bound: 432KB/CU/K-step vs 920cy MFMA). MFMA order bit-identical.
__global__ __launch_bounds__(256, 2) void k1_mfma(
    const u16* __restrict__ Xh, const u16* __restrict__ Xm, const u16* __restrict__ Xl,
    const u16* __restrict__ W1h, const u16* __restrict__ W1m, const u16* __restrict__ W1l,
    const float* __restrict__ b1,
    const u16* __restrict__ W2h, const u16* __restrict__ W2m, const u16* __restrict__ W2l,
    const float* __restrict__ b2, float* __restrict__ fv)
{
  __shared__ __align__(16) unsigned char sm[73728];
  unsigned char* xsr = sm;          // 3 * 8192  (A1s tile, phase B only)
  unsigned char* wsr = sm + 24576;  // 3 * 16384 (W1 / W2 tile)

  const int t  = threadIdx.x;
  const int l  = t & 63;
  const int wn = t >> 6;
  const int g  = (l >> 4) & 3;
  const int lr = l & 15;
  const int bid = blockIdx.x;
  const int swz = (bid & 7)*64 + (bid >> 3);   // 512 blocks, bijective
  const int row0 = swz * 64;

  f32x4 fvacc[4][2];
  #pragma unroll
  for (int mf=0;mf<4;++mf){
    fvacc[mf][0] = (f32x4){0.f,0.f,0.f,0.f};
    fvacc[mf][1] = (f32x4){0.f,0.f,0.f,0.f};
  }

  // per-thread X fragment row base (row = row0 + mf*16 + lr)
  const size_t xrow = (size_t)(row0 + lr)*768;

  #pragma unroll 1
  for (int nc = 0; nc < 16; ++nc){
    f32x4 a1acc[4][2];
    #pragma unroll
    for (int mf=0;mf<4;++mf){
      a1acc[mf][0] = (f32x4){0.f,0.f,0.f,0.f};
      a1acc[mf][1] = (f32x4){0.f,0.f,0.f,0.f};
    }

    // Phase A: A1 = X @ W1[:, nc*128 : +128]; A frags direct from global
    #pragma unroll 1
    for (int ks = 0; ks < 12; ++ks){
      #pragma unroll
      for (int i=0;i<12;++i){
        const int ci = wn*12 + i;
        const int s  = ci >> 4;
        const int rb = ci & 15;
        const int rloc = rb*8 + (l >> 3);
        const int q  = l & 7;
        const u16* Wp = (s==0) ? W1h : ((s==1) ? W1m : W1l);
        const u16* src = Wp + (size_t)(nc*128 + rloc)*768 + ks*64 + ((q ^ (rloc & 7)) << 3);
        gload16(src, wsr + s*16384 + rb*1024);
      }
      __syncthreads();

      #pragma unroll
      for (int kk=0;kk<2;++kk){
        s16x8 Bf[3][2];
        #pragma unroll
        for (int s=0;s<3;++s){
          #pragma unroll
          for (int nf=0;nf<2;++nf){
            const int br = wn*32 + nf*16 + lr;
            Bf[s][nf] = *(const s16x8*)(wsr + s*16384 + br*128 + ((16*(g + 4*kk)) ^ ((br & 7) << 4)));
          }
        }
        const size_t ko = (size_t)(ks*64 + kk*32 + g*8);
        #pragma unroll
        for (int mf=0;mf<4;++mf){
          const size_t ao = xrow + (size_t)mf*16*768 + ko;
          const s16x8 A0 = *(const s16x8*)&Xh[ao];
          const s16x8 A1 = *(const s16x8*)&Xm[ao];
          const s16x8 A2 = *(const s16x8*)&Xl[ao];
          #pragma unroll
          for (int nf=0;nf<2;++nf){
            f32x4 acc = a1acc[mf][nf];
            acc = MFMA16(A0, Bf[0][nf], acc);
            acc = MFMA16(A0, Bf[1][nf], acc);
            acc = MFMA16(A1, Bf[0][nf], acc);
            acc = MFMA16(A1, Bf[1][nf], acc);
            acc = MFMA16(A0, Bf[2][nf], acc);
            acc = MFMA16(A2, Bf[0][nf], acc);
            a1acc[mf][nf] = acc;
          }
        }
      }
      __syncthreads();
    }

    // Phase B: fv += relu(A1+b1) @ W2[nc chunk]
    const float b1v0 = b1[nc*128 + wn*32 + lr];
    const float b1v1 = b1[nc*128 + wn*32 + 16 + lr];

    #pragma unroll
    for (int half=0; half<2; ++half){
      if ((wn >> 1) == half){
        #pragma unroll
        for (int mf=0;mf<4;++mf){
          #pragma unroll
          for (int nf=0;nf<2;++nf){
            const int klocal = (wn & 1)*32 + nf*16 + lr;
            #pragma unroll
            for (int r=0;r<4;++r){
              float vv = a1acc[mf][nf][r] + ((nf==0) ? b1v0 : b1v1);
              vv = vv > 0.f ? vv : 0.f;
              u16 sh, sm2, sl;
              split3(vv, sh, sm2, sl);
              const int ar = mf*16 + g*4 + r;
              const int bo = ar*128 + ((2*klocal) ^ ((ar & 7) << 4));
              *(u16*)(xsr + bo)         = sh;
              *(u16*)(xsr + 8192 + bo)  = sm2;
              *(u16*)(xsr + 16384 + bo) = sl;
            }
          }
        }
      }
      #pragma unroll
      for (int i=0;i<12;++i){
        const int ci = wn*12 + i;
        const int s  = ci >> 4;
        const int rb = ci & 15;
        const int rloc = rb*8 + (l >> 3);
        const int q  = l & 7;
        const u16* Wp = (s==0) ? W2h : ((s==1) ? W2m : W2l);
        const u16* src = Wp + (size_t)rloc*2048 + nc*128 + half*64 + ((q ^ (rloc & 7)) << 3);
        gload16(src, wsr + s*16384 + rb*1024);
      }
      __syncthreads();

      #pragma unroll
      for (int kk=0;kk<2;++kk){
        s16x8 Bf[3][2], Af[3][4];
        #pragma unroll
        for (int s=0;s<3;++s){
          #pragma unroll
          for (int nf=0;nf<2;++nf){
            const int br = wn*32 + nf*16 + lr;
            Bf[s][nf] = *(const s16x8*)(wsr + s*16384 + br*128 + ((16*(g + 4*kk)) ^ ((br & 7) << 4)));
          }
          #pragma unroll
          for (int mf=0;mf<4;++mf){
            const int ar = mf*16 + lr;
            Af[s][mf] = *(const s16x8*)(xsr + s*8192 + ar*128 + ((16*(g + 4*kk)) ^ ((ar & 7) << 4)));
          }
        }
        #pragma unroll
        for (int mf=0;mf<4;++mf){
          #pragma unroll
          for (int nf=0;nf<2;++nf){
            f32x4 acc = fvacc[mf][nf];
            acc = MFMA16(Af[0][mf], Bf[0][nf], acc);
            acc = MFMA16(Af[0][mf], Bf[1][nf], acc);
            acc = MFMA16(Af[1][mf], Bf[0][nf], acc);
            acc = MFMA16(Af[1][mf], Bf[1][nf], acc);
            acc = MFMA16(Af[0][mf], Bf[2][nf], acc);
            acc = MFMA16(Af[2][mf], Bf[0][nf], acc);
            fvacc[mf][nf] = acc;
          }
        }
      }
      __syncthreads();
    }
  }

  const float b2v0 = b2[wn*32 + lr];
  const float b2v1 = b2[wn*32 + 16 + lr];
  #pragma unroll
  for (int mf=0;mf<4;++mf){
    #pragma unroll
    for (int nf=0;nf<2;++nf){
      #pragma unroll
      for (int r=0;r<4;++r){
        const int frow = row0 + mf*16 + g*4 + r;
        const int col  = wn*32 + nf*16 + lr;
        fv[(size_t)frow*NZ + col] = fvacc[mf][nf][r] + ((nf==0) ? b2v0 : b2v1);
      }
    }
  }
}

// ---------------- K2: MFMA cdist -> Q0 = exp(-2*dist), row-major [BN][NCN] -------
__global__ __launch_bounds__(256, 2) void k2_mfma(
    const u16* __restrict__ fvh, const u16* __restrict__ fvm, const u16* __restrict__ fvl,
    const u16* __restrict__ ch,  const u16* __restrict__ cm,  const u16* __restrict__ cl,
    const float* __restrict__ fvn, const float* __restrict__ cn,
    float* __restrict__ Q0)
{
  __shared__ __align__(16) unsigned char bs[49152];
  __shared__ float cnl[NCN];
  const int t  = threadIdx.x;
  const int l  = t & 63;
  const int wn = t >> 6;
  const int g  = (l >> 4) & 3;
  const int lr = l & 15;
  const int bid = blockIdx.x;
  const int swz = (bid & 7)*64 + (bid >> 3);
  const int row0 = swz * 64;
  const int arow = row0 + wn*16 + lr;

  s16x8 Af[3][4];
  #pragma unroll
  for (int kk=0;kk<4;++kk){
    const size_t ao = (size_t)arow*128 + kk*32 + g*8;
    Af[0][kk] = *(const s16x8*)&fvh[ao];
    Af[1][kk] = *(const s16x8*)&fvm[ao];
    Af[2][kk] = *(const s16x8*)&fvl[ao];
  }
  #pragma unroll
  for (int m=0;m<4;++m) cnl[t + 256*m] = cn[t + 256*m];
  const f32x4 fvnv = *(const f32x4*)&fvn[row0 + wn*16 + g*4];

  #pragma unroll 1
  for (int cc = 0; cc < NCN; cc += 64){
    #pragma unroll
    for (int i=0;i<12;++i){
      const int ci = wn*12 + i;
      const int s  = ci >> 4;
      const int rb = ci & 15;
      const int crow = rb*4 + (l >> 4);
      const int q  = l & 15;
      const u16* Cp = (s==0) ? ch : ((s==1) ? cm : cl);
      const u16* src = Cp + (size_t)(cc + crow)*128 + ((q ^ (crow & 15)) << 3);
      gload16(src, bs + s*16384 + rb*1024);
    }
    __syncthreads();

    f32x4 acc[4];
    #pragma unroll
    for (int nf=0;nf<4;++nf) acc[nf] = (f32x4){0.f,0.f,0.f,0.f};

    #pragma unroll
    for (int kk=0;kk<4;++kk){
      s16x8 Bq[3][4];
      #pragma unroll
      for (int nf=0;nf<4;++nf){
        const int br = nf*16 + lr;
        const int base = br*256 + (((g + 4*kk) ^ (br & 15)) << 4);
        Bq[0][nf] = *(const s16x8*)(bs + base);
        Bq[1][nf] = *(const s16x8*)(bs + 16384 + base);
        Bq[2][nf] = *(const s16x8*)(bs + 32768 + base);
      }
      #pragma unroll
      for (int nf=0;nf<4;++nf){
        f32x4 a = acc[nf];
        a = MFMA16(Af[0][kk], Bq[0][nf], a);
        a = MFMA16(Af[0][kk], Bq[1][nf], a);
        a = MFMA16(Af[1][kk], Bq[0][nf], a);
        a = MFMA16(Af[1][kk], Bq[1][nf], a);
        a = MFMA16(Af[0][kk], Bq[2][nf], a);
        a = MFMA16(Af[2][kk], Bq[0][nf], a);
        acc[nf] = a;
      }
    }

    #pragma unroll
    for (int nf=0;nf<4;++nf){
      const int n = cc + nf*16 + lr;
      const float cv = cnl[n];
      #pragma unroll
      for (int r=0;r<4;++r){
        float sq = fvnv[r] + cv - 2.0f*acc[nf][r];
        sq = sq > 1e-12f ? sq : 1e-12f;
        const float d = sqrtf(sq);
        Q0[(size_t)(row0 + wn*16 + g*4 + r)*NCN + n] = expf(-2.0f*d);
      }
    }
    __syncthreads();
  }
}

// ---------------- K3: one fused sinkhorn pass (R6 config) ----------------
__global__ __launch_bounds__(256, 2) void k3_pass(
    const float* __restrict__ Q0, const float* __restrict__ u,
    float* __restrict__ S_part, float alpha)
{
  __shared__ __align__(16) float Sw[4][NCN];
  const int t = threadIdx.x;
  const int w = t >> 6, l = t & 63;

  f32x4 uu[4], sacc[4];
  #pragma unroll
  for (int j=0;j<4;++j){
    uu[j] = *(const f32x4*)&u[4*(l + 64*j)];
    sacc[j] = (f32x4){0.f,0.f,0.f,0.f};
  }

  const int gw = blockIdx.x*4 + w;          // 0..2047
  const size_t b0 = (size_t)gw * 16;
  #pragma unroll 1
  for (int rr=0; rr<16; rr+=4){
    f32x4 q[4][4];
    float part[4];
    #pragma unroll
    for (int rq=0;rq<4;++rq){
      const f32x4* qrow = (const f32x4*)(Q0 + (b0 + rr + rq)*NCN);
      float p = 0.f;
      #pragma unroll
      for (int j=0;j<4;++j){
        q[rq][j] = qrow[l + 64*j];
        p += q[rq][j][0]*uu[j][0]; p += q[rq][j][1]*uu[j][1];
        p += q[rq][j][2]*uu[j][2]; p += q[rq][j][3]*uu[j][3];
      }
      part[rq] = p;
    }
    #pragma unroll
    for (int off=32; off; off>>=1){
      #pragma unroll
      for (int rq=0;rq<4;++rq) part[rq] += __shfl_xor(part[rq], off, 64);
    }
    #pragma unroll
    for (int rq=0;rq<4;++rq){
      const float v = alpha / part[rq];
      #pragma unroll
      for (int j=0;j<4;++j){
        sacc[j][0] += q[rq][j][0]*v; sacc[j][1] += q[rq][j][1]*v;
        sacc[j][2] += q[rq][j][2]*v; sacc[j][3] += q[rq][j][3]*v;
      }
    }
  }
  #pragma unroll
  for (int j=0;j<4;++j) *(f32x4*)&Sw[w][4*(l + 64*j)] = sacc[j];
  __syncthreads();
  #pragma unroll
  for (int m=0;m<4;++m){
    int k = t + 256*m;
    S_part[(size_t)blockIdx.x*NCN + k] = ((Sw[0][k]+Sw[1][k])+(Sw[2][k]+Sw[3][k]));
  }
}

// ---------------- K4: u = r / colsum(S_part over 512 rows) ----------------
__global__ __launch_bounds__(256) void k4_unew(
    const float* __restrict__ S_part, float* __restrict__ u)
{
  __shared__ float P[256];
  const int t = threadIdx.x;
  const int c = t & 15;
  const int seg = t >> 4;
  const int col = blockIdx.x*16 + c;
  float p = 0.f;
  #pragma unroll 4
  for (int i=0;i<32;++i)
    p += S_part[(size_t)(seg*32 + i)*NCN + col];
  P[seg*16 + c] = p;
  __syncthreads();
  #pragma unroll
  for (int s2=8; s2>0; s2>>=1){
    if (seg < s2) P[seg*16 + c] += P[(seg+s2)*16 + c];
    __syncthreads();
  }
  if (seg == 0) u[col] = (1.0f/1024.0f) / P[c];
}

// ---------------- K5: final pass (512 blocks, 16 rows/wave) ----------------
__global__ __launch_bounds__(256, 2) void k5_final(
    const float* __restrict__ Q0, const float* __restrict__ u,
    float* __restrict__ softc_part, float* __restrict__ loss_part,
    int* __restrict__ hist_raw, int* __restrict__ hist_clu,
    float* __restrict__ out_ba)
{
  __shared__ __align__(16) float Sw[4][NCN];
  __shared__ float lossw[4];
  const int t = threadIdx.x;
  const int w = t >> 6, l = t & 63;

  f32x4 uu[4], sacc[4];
  #pragma unroll
  for (int j=0;j<4;++j){
    uu[j] = *(const f32x4*)&u[4*(l + 64*j)];
    sacc[j] = (f32x4){0.f,0.f,0.f,0.f};
  }

  const int gw = blockIdx.x*4 + w;          // 0..2047
  const size_t b0 = (size_t)gw * 16;
  float lacc = 0.f;
  #pragma unroll 1
  for (int rr=0; rr<16; ++rr){
    const size_t b = b0 + rr;
    const f32x4* qrow = (const f32x4*)(Q0 + b*NCN);
    f32x4 q4[4], wv4[4];
    float part = 0.f;
    #pragma unroll
    for (int j=0;j<4;++j){
      q4[j] = qrow[l + 64*j];
      wv4[j][0] = uu[j][0]*q4[j][0]; wv4[j][1] = uu[j][1]*q4[j][1];
      wv4[j][2] = uu[j][2]*q4[j][2]; wv4[j][3] = uu[j][3]*q4[j][3];
      part += wv4[j][0]; part += wv4[j][1]; part += wv4[j][2]; part += wv4[j][3];
    }
    #pragma unroll
    for (int off=32; off; off>>=1) part += __shfl_xor(part, off, 64);
    const float inv = 1.0f / part;

    float smin = wv4[0][0] * inv; int kmin = 4*l; float qat = q4[0][0];
    float qmax = q4[0][0];        int kmax = 4*l;
    #pragma unroll
    for (int j=0;j<4;++j){
      #pragma unroll
      for (int c=0;c<4;++c){
        if (j==0 && c==0) continue;
        const float qv = q4[j][c];
        const float sv = wv4[j][c] * inv;
        const int k = 4*(l + 64*j) + c;
        if (sv < smin){ smin = sv; kmin = k; qat = qv; }
        if (qv > qmax){ qmax = qv; kmax = k; }
      }
    }
    #pragma unroll
    for (int off=32; off; off>>=1){
      float s2 = __shfl_xor(smin, off, 64);
      int   k2 = __shfl_xor(kmin, off, 64);
      float q2 = __shfl_xor(qat,  off, 64);
      if (s2 < smin || (s2 == smin && k2 < kmin)){ smin=s2; kmin=k2; qat=q2; }
      float m2 = __shfl_xor(qmax, off, 64);
      int   i2 = __shfl_xor(kmax, off, 64);
      if (m2 > qmax || (m2 == qmax && i2 < kmax)){ qmax=m2; kmax=i2; }
    }
    #pragma unroll
    for (int j=0;j<4;++j){
      sacc[j][0] += wv4[j][0]*inv; sacc[j][1] += wv4[j][1]*inv;
      sacc[j][2] += wv4[j][2]*inv; sacc[j][3] += wv4[j][3]*inv;
    }
    if (l == 0){
      out_ba[b] = (float)kmin;
      atomicAdd(&hist_clu[kmin], 1);
      atomicAdd(&hist_raw[kmax], 1);
      lacc += -0.5f * logf(qat);
    }
  }
  #pragma unroll
  for (int j=0;j<4;++j) *(f32x4*)&Sw[w][4*(l + 64*j)] = sacc[j];
  if (l == 0) lossw[w] = lacc;
  __syncthreads();
  #pragma unroll
  for (int m=0;m<4;++m){
    int k = t + 256*m;
    softc_part[(size_t)blockIdx.x*NCN + k] = ((Sw[0][k]+Sw[1][k])+(Sw[2][k]+Sw[3][k]));
  }
  if (t == 0) loss_part[blockIdx.x] = ((lossw[0]+lossw[1])+(lossw[2]+lossw[3]));
}

// ---------------- K6: deterministic combine + output write ----------------
__global__ __launch_bounds__(1024) void k6_fin(
    const float* __restrict__ softc_part, const float* __restrict__ loss_part,
    const int* __restrict__ hist_raw, const int* __restrict__ hist_clu,
    const int* __restrict__ raw_in, const int* __restrict__ clu_in,
    const float* __restrict__ tsoft_in, float* __restrict__ out)
{
  const int k = threadIdx.x;
  float s0=0.f,s1=0.f,s2=0.f,s3=0.f;
  for (int blk=0; blk<512; blk+=4){
    s0 += softc_part[(size_t)(blk+0)*NCN + k];
    s1 += softc_part[(size_t)(blk+1)*NCN + k];
    s2 += softc_part[(size_t)(blk+2)*NCN + k];
    s3 += softc_part[(size_t)(blk+3)*NCN + k];
  }
  const float s = ((s0+s1)+(s2+s3));
  out[1 + BN + k]           = s;
  out[1 + BN + NCN + k]     = (float)(raw_in[k] + hist_raw[k]);
  out[1 + BN + 2*NCN + k]   = (float)(clu_in[k] + hist_clu[k]);
  out[1 + BN + 3*NCN + k]   = tsoft_in[k] + s;
  if (k == 0){
    float ls = 0.f;
    for (int i=0;i<512;++i) ls += loss_part[i];
    out[0] = ls / 32768.0f;
  }
}

extern "C" void kernel_launch(void* const* d_in, const int* in_sizes, int n_in,
                              void* d_out, int out_size, void* d_ws, size_t ws_size,
                              hipStream_t stream) {
  (void)in_sizes; (void)n_in; (void)out_size; (void)ws_size;
  const float* x      = (const float*)d_in[0];
  const float* W1     = (const float*)d_in[1];
  const float* b1     = (const float*)d_in[2];
  const float* W2     = (const float*)d_in[3];
  const float* b2     = (const float*)d_in[4];
  const float* cent   = (const float*)d_in[5];
  const int*   clu_in = (const int*)d_in[6];
  const int*   raw_in = (const int*)d_in[7];
  const float* tsoft  = (const float*)d_in[8];
  float* out = (float*)d_out;

  // ws layout (float units). Lifetime aliasing:
  //  - X-splits (k1-only) overlay Q0 + its tail slack.
  //  - softc_par/loss_par live in the slack behind Q0 (dead before k5).
  //  - fv/cent splits overlay W splits (dead after k1).
  float* ws        = (float*)d_ws;
  float* fv        = ws;                        // 4,194,304 floats
  float* Q0        = ws + 4194304;              // 33,554,432 floats
  u16*   Xh        = (u16*)Q0;                  // 3 x 25,165,824 u16
  u16*   Xm        = Xh + 25165824;
  u16*   Xl        = Xm + 25165824;
  float* softc_par = ws + 37748736;             // 524,288 (slack behind Q0)
  float* loss_par  = softc_par + 524288;        // 512
  float* u         = ws + 41943040;             // 1024
  float* S_part    = u + 1024;                  // 524,288 (512x1024)
  int*   hist_raw  = (int*)(S_part + 524288);   // 1024 ints
  int*   hist_clu  = hist_raw + 1024;           // 1024 ints
  float* wbase     = (float*)(hist_clu + 1024); // union region
  u16* W1Th = (u16*)wbase;
  u16* W1Tm = W1Th + 1572864;
  u16* W1Tl = W1Tm + 1572864;
  u16* W2Th = W1Tl + 1572864;
  u16* W2Tm = W2Th + 262144;
  u16* W2Tl = W2Tm + 262144;
  u16* fvh = (u16*)wbase;
  u16* fvm = fvh + 4194304;
  u16* fvl = fvm + 4194304;
  u16* ch  = fvl + 4194304;
  u16* cm  = ch  + 131072;
  u16* cl  = cm  + 131072;
  float* fvn = wbase + 6488064;                 // 32,768
  float* cn  = fvn + 32768;                     // 1,024
  float* out_ba = out + 1;

  c_split <<<24576, 256, 0, stream>>>(x, Xh, Xm, Xl, 6291456);
  c_tsplit<<<dim3(12, 32), 256, 0, stream>>>(W1, 768, 2048, W1Th, W1Tm, W1Tl);
  c_tsplit<<<dim3(32, 2),  256, 0, stream>>>(W2, 2048, 128, W2Th, W2Tm, W2Tl);
  k0_init<<<1, 1024, 0, stream>>>(u, hist_raw, hist_clu);

  k1_mfma<<<512, 256, 0, stream>>>(Xh, Xm, Xl, W1Th, W1Tm, W1Tl, b1,
                                   W2Th, W2Tm, W2Tl, b2, fv);

  c_split<<<4096, 256, 0, stream>>>(fv,   fvh, fvm, fvl, 1048576);
  c_split<<<128,  256, 0, stream>>>(cent, ch,  cm,  cl,  32768);
  c_norm <<<8192, 256, 0, stream>>>(fv,   fvn);
  c_norm <<<256,  256, 0, stream>>>(cent, cn);

  k2_mfma<<<512, 256, 0, stream>>>(fvh, fvm, fvl, ch, cm, cl, fvn, cn, Q0);

  for (int it = 0; it < 15; ++it){
    const float alpha = (it == 0) ? 1.0f : (1.0f/32768.0f);
    k3_pass<<<512, 256, 0, stream>>>(Q0, u, S_part, alpha);
    k4_unew<<<64, 256, 0, stream>>>(S_part, u);
  }
  k5_final<<<512, 256, 0, stream>>>(Q0, u, softc_par, loss_par,
                                    hist_raw, hist_clu, out_ba);
  k6_fin<<<1, 1024, 0, stream>>>(softc_par, loss_par, hist_raw, hist_clu,
                                 raw_in, clu_in, tsoft, out);
}

// Round 10
// 1322.931 us; speedup vs baseline: 1.5226x; 1.5226x over previous
//
#include <hip/hip_runtime.h>
#include <math.h>

// Problem constants (B, D_IN, H, NZ, NC)
#define BN    32768
#define DIN   768
#define HN    2048
#define NZ    128
#define NCN   1024

typedef __attribute__((ext_vector_type(8))) short s16x8;
typedef __attribute__((ext_vector_type(4))) float f32x4;
typedef unsigned short u16;

#define MFMA16(a,b,c) __builtin_amdgcn_mfma_f32_16x16x32_bf16(a,b,c,0,0,0)

__device__ __forceinline__ u16 bf16_rne(float x){
  unsigned u = __float_as_uint(x);
  unsigned r = (u + 0x7FFFu + ((u >> 16) & 1u)) >> 16;
  return (u16)r;
}
__device__ __forceinline__ float bf16_tof(u16 h){
  return __uint_as_float(((unsigned)h) << 16);
}
__device__ __forceinline__ void split3(float x, u16& h, u16& m, u16& l){
  h = bf16_rne(x);
  float r1 = x - bf16_tof(h);
  m = bf16_rne(r1);
  float r2 = r1 - bf16_tof(m);
  l = bf16_rne(r2);
}

__device__ __forceinline__ void gload16(const void* gsrc, void* lds){
  __builtin_amdgcn_global_load_lds(
      (const __attribute__((address_space(1))) unsigned int*)gsrc,
      (__attribute__((address_space(3))) unsigned int*)lds, 16, 0, 0);
}

// ---------------- K0: init (u=1, histograms=0) ----------------
__global__ __launch_bounds__(1024) void k0_init(float* u, int* hraw, int* hclu){
  const int k = threadIdx.x;
  u[k] = 1.0f;
  hraw[k] = 0;
  hclu[k] = 0;
}

// ---------------- Convert: elementwise 3-way bf16 split ----------------
__global__ __launch_bounds__(256) void c_split(
    const float* __restrict__ in, u16* __restrict__ oh, u16* __restrict__ om,
    u16* __restrict__ ol, int n4)
{
  const int i = blockIdx.x*256 + threadIdx.x;
  if (i >= n4) return;
  const f32x4 v = *(const f32x4*)&in[(size_t)i*4];
  ushort4 h4, m4, l4;
  split3(v[0], h4.x, m4.x, l4.x);
  split3(v[1], h4.y, m4.y, l4.y);
  split3(v[2], h4.z, m4.z, l4.z);
  split3(v[3], h4.w, m4.w, l4.w);
  *(ushort4*)&oh[(size_t)i*4] = h4;
  *(ushort4*)&om[(size_t)i*4] = m4;
  *(ushort4*)&ol[(size_t)i*4] = l4;
}

// ---------------- Convert: transpose + 3-way bf16 split ----------------
__global__ __launch_bounds__(256) void c_tsplit(
    const float* __restrict__ in, int R, int C,
    u16* __restrict__ oh, u16* __restrict__ om, u16* __restrict__ ol)
{
  __shared__ float L[64][65];
  const int t = threadIdx.x;
  const int bi = blockIdx.x, bj = blockIdx.y;
  #pragma unroll
  for (int m=0;m<4;++m){
    int flat = t + 256*m;
    int r = flat >> 4, c4 = (flat & 15) << 2;
    const float4 v = *(const float4*)&in[(size_t)(bi*64 + r)*C + bj*64 + c4];
    L[r][c4+0] = v.x; L[r][c4+1] = v.y; L[r][c4+2] = v.z; L[r][c4+3] = v.w;
  }
  __syncthreads();
  #pragma unroll
  for (int m=0;m<4;++m){
    int flat = t + 256*m;
    int oc = flat >> 4, k4 = (flat & 15) << 2;
    ushort4 h4, m4, l4;
    split3(L[k4+0][oc], h4.x, m4.x, l4.x);
    split3(L[k4+1][oc], h4.y, m4.y, l4.y);
    split3(L[k4+2][oc], h4.z, m4.z, l4.z);
    split3(L[k4+3][oc], h4.w, m4.w, l4.w);
    size_t off = (size_t)(bj*64 + oc)*R + bi*64 + k4;
    *(ushort4*)&oh[off] = h4;
    *(ushort4*)&om[off] = m4;
    *(ushort4*)&ol[off] = l4;
  }
}

// ---------------- Convert: row sum-of-squares, rows of 128 ----------------
__global__ __launch_bounds__(256) void c_norm(
    const float* __restrict__ in, float* __restrict__ out)
{
  const int w = threadIdx.x >> 6, l = threadIdx.x & 63;
  const int row = blockIdx.x*4 + w;
  const float2 v = *(const float2*)&in[(size_t)row*128 + l*2];
  float s = v.x*v.x + v.y*v.y;
  #pragma unroll
  for (int off=32; off; off>>=1) s += __shfl_xor(s, off, 64);
  if (l == 0) out[row] = s;
}

// ---------------- K1: fused MFMA backbone fv = relu(X@W1+b1)@W2 + b2 ----------------
// R6 structure (known-good 674us, no spills) + bijective XCD swizzle.
__global__ __launch_bounds__(256, 2) void k1_mfma(
    const u16* __restrict__ Xh, const u16* __restrict__ Xm, const u16* __restrict__ Xl,
    const u16* __restrict__ W1h, const u16* __restrict__ W1m, const u16* __restrict__ W1l,
    const float* __restrict__ b1,
    const u16* __restrict__ W2h, const u16* __restrict__ W2m, const u16* __restrict__ W2l,
    const float* __restrict__ b2, float* __restrict__ fv)
{
  __shared__ __align__(16) unsigned char sm[73728];
  unsigned char* xsr = sm;          // 3 * 8192
  unsigned char* wsr = sm + 24576;  // 3 * 16384

  const int t  = threadIdx.x;
  const int l  = t & 63;
  const int wn = t >> 6;
  const int g  = (l >> 4) & 3;
  const int lr = l & 15;
  const int bid = blockIdx.x;
  const int swz = (bid & 7)*64 + (bid >> 3);   // 512 blocks, bijective
  const int row0 = swz * 64;

  f32x4 fvacc[4][2];
  #pragma unroll
  for (int mf=0;mf<4;++mf){
    fvacc[mf][0] = (f32x4){0.f,0.f,0.f,0.f};
    fvacc[mf][1] = (f32x4){0.f,0.f,0.f,0.f};
  }

  #pragma unroll 1
  for (int nc = 0; nc < 16; ++nc){
    f32x4 a1acc[4][2];
    #pragma unroll
    for (int mf=0;mf<4;++mf){
      a1acc[mf][0] = (f32x4){0.f,0.f,0.f,0.f};
      a1acc[mf][1] = (f32x4){0.f,0.f,0.f,0.f};
    }

    // Phase A: A1 = X @ W1[:, nc*128 : +128]
    #pragma unroll 1
    for (int ks = 0; ks < 12; ++ks){
      #pragma unroll
      for (int i=0;i<6;++i){
        const int ci = wn*6 + i;
        const int s  = ci >> 3;
        const int rb = ci & 7;
        const int xr = rb*8 + (l >> 3);
        const int q  = l & 7;
        const u16* Xp = (s==0) ? Xh : ((s==1) ? Xm : Xl);
        const u16* src = Xp + (size_t)(row0 + xr)*768 + ks*64 + ((q ^ (xr & 7)) << 3);
        gload16(src, xsr + s*8192 + rb*1024);
      }
      #pragma unroll
      for (int i=0;i<12;++i){
        const int ci = wn*12 + i;
        const int s  = ci >> 4;
        const int rb = ci & 15;
        const int rloc = rb*8 + (l >> 3);
        const int q  = l & 7;
        const u16* Wp = (s==0) ? W1h : ((s==1) ? W1m : W1l);
        const u16* src = Wp + (size_t)(nc*128 + rloc)*768 + ks*64 + ((q ^ (rloc & 7)) << 3);
        gload16(src, wsr + s*16384 + rb*1024);
      }
      __syncthreads();

      #pragma unroll
      for (int kk=0;kk<2;++kk){
        s16x8 Bf[3][2], Af[3][4];
        #pragma unroll
        for (int s=0;s<3;++s){
          #pragma unroll
          for (int nf=0;nf<2;++nf){
            const int br = wn*32 + nf*16 + lr;
            Bf[s][nf] = *(const s16x8*)(wsr + s*16384 + br*128 + ((16*(g + 4*kk)) ^ ((br & 7) << 4)));
          }
          #pragma unroll
          for (int mf=0;mf<4;++mf){
            const int ar = mf*16 + lr;
            Af[s][mf] = *(const s16x8*)(xsr + s*8192 + ar*128 + ((16*(g + 4*kk)) ^ ((ar & 7) << 4)));
          }
        }
        #pragma unroll
        for (int mf=0;mf<4;++mf){
          #pragma unroll
          for (int nf=0;nf<2;++nf){
            f32x4 acc = a1acc[mf][nf];
            acc = MFMA16(Af[0][mf], Bf[0][nf], acc);
            acc = MFMA16(Af[0][mf], Bf[1][nf], acc);
            acc = MFMA16(Af[1][mf], Bf[0][nf], acc);
            acc = MFMA16(Af[1][mf], Bf[1][nf], acc);
            acc = MFMA16(Af[0][mf], Bf[2][nf], acc);
            acc = MFMA16(Af[2][mf], Bf[0][nf], acc);
            a1acc[mf][nf] = acc;
          }
        }
      }
      __syncthreads();
    }

    // Phase B: fv += relu(A1+b1) @ W2[nc chunk]
    const float b1v0 = b1[nc*128 + wn*32 + lr];
    const float b1v1 = b1[nc*128 + wn*32 + 16 + lr];

    #pragma unroll
    for (int half=0; half<2; ++half){
      if ((wn >> 1) == half){
        #pragma unroll
        for (int mf=0;mf<4;++mf){
          #pragma unroll
          for (int nf=0;nf<2;++nf){
            const int klocal = (wn & 1)*32 + nf*16 + lr;
            #pragma unroll
            for (int r=0;r<4;++r){
              float vv = a1acc[mf][nf][r] + ((nf==0) ? b1v0 : b1v1);
              vv = vv > 0.f ? vv : 0.f;
              u16 sh, sm2, sl;
              split3(vv, sh, sm2, sl);
              const int ar = mf*16 + g*4 + r;
              const int bo = ar*128 + ((2*klocal) ^ ((ar & 7) << 4));
              *(u16*)(xsr + bo)         = sh;
              *(u16*)(xsr + 8192 + bo)  = sm2;
              *(u16*)(xsr + 16384 + bo) = sl;
            }
          }
        }
      }
      #pragma unroll
      for (int i=0;i<12;++i){
        const int ci = wn*12 + i;
        const int s  = ci >> 4;
        const int rb = ci & 15;
        const int rloc = rb*8 + (l >> 3);
        const int q  = l & 7;
        const u16* Wp = (s==0) ? W2h : ((s==1) ? W2m : W2l);
        const u16* src = Wp + (size_t)rloc*2048 + nc*128 + half*64 + ((q ^ (rloc & 7)) << 3);
        gload16(src, wsr + s*16384 + rb*1024);
      }
      __syncthreads();

      #pragma unroll
      for (int kk=0;kk<2;++kk){
        s16x8 Bf[3][2], Af[3][4];
        #pragma unroll
        for (int s=0;s<3;++s){
          #pragma unroll
          for (int nf=0;nf<2;++nf){
            const int br = wn*32 + nf*16 + lr;
            Bf[s][nf] = *(const s16x8*)(wsr + s*16384 + br*128 + ((16*(g + 4*kk)) ^ ((br & 7) << 4)));
          }
          #pragma unroll
          for (int mf=0;mf<4;++mf){
            const int ar = mf*16 + lr;
            Af[s][mf] = *(const s16x8*)(xsr + s*8192 + ar*128 + ((16*(g + 4*kk)) ^ ((ar & 7) << 4)));
          }
        }
        #pragma unroll
        for (int mf=0;mf<4;++mf){
          #pragma unroll
          for (int nf=0;nf<2;++nf){
            f32x4 acc = fvacc[mf][nf];
            acc = MFMA16(Af[0][mf], Bf[0][nf], acc);
            acc = MFMA16(Af[0][mf], Bf[1][nf], acc);
            acc = MFMA16(Af[1][mf], Bf[0][nf], acc);
            acc = MFMA16(Af[1][mf], Bf[1][nf], acc);
            acc = MFMA16(Af[0][mf], Bf[2][nf], acc);
            acc = MFMA16(Af[2][mf], Bf[0][nf], acc);
            fvacc[mf][nf] = acc;
          }
        }
      }
      __syncthreads();
    }
  }

  const float b2v0 = b2[wn*32 + lr];
  const float b2v1 = b2[wn*32 + 16 + lr];
  #pragma unroll
  for (int mf=0;mf<4;++mf){
    #pragma unroll
    for (int nf=0;nf<2;++nf){
      #pragma unroll
      for (int r=0;r<4;++r){
        const int frow = row0 + mf*16 + g*4 + r;
        const int col  = wn*32 + nf*16 + lr;
        fv[(size_t)frow*NZ + col] = fvacc[mf][nf][r] + ((nf==0) ? b2v0 : b2v1);
      }
    }
  }
}

// ---------------- K2: MFMA cdist -> Q0 = exp(-2*dist), row-major [BN][NCN] -------
__global__ __launch_bounds__(256, 2) void k2_mfma(
    const u16* __restrict__ fvh, const u16* __restrict__ fvm, const u16* __restrict__ fvl,
    const u16* __restrict__ ch,  const u16* __restrict__ cm,  const u16* __restrict__ cl,
    const float* __restrict__ fvn, const float* __restrict__ cn,
    float* __restrict__ Q0)
{
  __shared__ __align__(16) unsigned char bs[49152];
  __shared__ float cnl[NCN];
  const int t  = threadIdx.x;
  const int l  = t & 63;
  const int wn = t >> 6;
  const int g  = (l >> 4) & 3;
  const int lr = l & 15;
  const int bid = blockIdx.x;
  const int swz = (bid & 7)*64 + (bid >> 3);
  const int row0 = swz * 64;
  const int arow = row0 + wn*16 + lr;

  s16x8 Af[3][4];
  #pragma unroll
  for (int kk=0;kk<4;++kk){
    const size_t ao = (size_t)arow*128 + kk*32 + g*8;
    Af[0][kk] = *(const s16x8*)&fvh[ao];
    Af[1][kk] = *(const s16x8*)&fvm[ao];
    Af[2][kk] = *(const s16x8*)&fvl[ao];
  }
  #pragma unroll
  for (int m=0;m<4;++m) cnl[t + 256*m] = cn[t + 256*m];
  const f32x4 fvnv = *(const f32x4*)&fvn[row0 + wn*16 + g*4];

  #pragma unroll 1
  for (int cc = 0; cc < NCN; cc += 64){
    #pragma unroll
    for (int i=0;i<12;++i){
      const int ci = wn*12 + i;
      const int s  = ci >> 4;
      const int rb = ci & 15;
      const int crow = rb*4 + (l >> 4);
      const int q  = l & 15;
      const u16* Cp = (s==0) ? ch : ((s==1) ? cm : cl);
      const u16* src = Cp + (size_t)(cc + crow)*128 + ((q ^ (crow & 15)) << 3);
      gload16(src, bs + s*16384 + rb*1024);
    }
    __syncthreads();

    f32x4 acc[4];
    #pragma unroll
    for (int nf=0;nf<4;++nf) acc[nf] = (f32x4){0.f,0.f,0.f,0.f};

    #pragma unroll
    for (int kk=0;kk<4;++kk){
      s16x8 Bq[3][4];
      #pragma unroll
      for (int nf=0;nf<4;++nf){
        const int br = nf*16 + lr;
        const int base = br*256 + (((g + 4*kk) ^ (br & 15)) << 4);
        Bq[0][nf] = *(const s16x8*)(bs + base);
        Bq[1][nf] = *(const s16x8*)(bs + 16384 + base);
        Bq[2][nf] = *(const s16x8*)(bs + 32768 + base);
      }
      #pragma unroll
      for (int nf=0;nf<4;++nf){
        f32x4 a = acc[nf];
        a = MFMA16(Af[0][kk], Bq[0][nf], a);
        a = MFMA16(Af[0][kk], Bq[1][nf], a);
        a = MFMA16(Af[1][kk], Bq[0][nf], a);
        a = MFMA16(Af[1][kk], Bq[1][nf], a);
        a = MFMA16(Af[0][kk], Bq[2][nf], a);
        a = MFMA16(Af[2][kk], Bq[0][nf], a);
        acc[nf] = a;
      }
    }

    #pragma unroll
    for (int nf=0;nf<4;++nf){
      const int n = cc + nf*16 + lr;
      const float cv = cnl[n];
      #pragma unroll
      for (int r=0;r<4;++r){
        float sq = fvnv[r] + cv - 2.0f*acc[nf][r];
        sq = sq > 1e-12f ? sq : 1e-12f;
        const float d = sqrtf(sq);
        Q0[(size_t)(row0 + wn*16 + g*4 + r)*NCN + n] = expf(-2.0f*d);
      }
    }
    __syncthreads();
  }
}

// ---------------- K3: one fused sinkhorn pass ----------------
// 512 blocks x 512 threads (8 waves, 16 waves/CU), 8 rows/wave,
// 4-row interleaved butterflies, register S, 8-wave LDS combine.
__global__ __launch_bounds__(512, 2) void k3_pass(
    const float* __restrict__ Q0, const float* __restrict__ u,
    float* __restrict__ S_part, float alpha)
{
  __shared__ __align__(16) float Sw[8][NCN];
  const int t = threadIdx.x;
  const int w = t >> 6, l = t & 63;

  f32x4 uu[4], sacc[4];
  #pragma unroll
  for (int j=0;j<4;++j){
    uu[j] = *(const f32x4*)&u[4*(l + 64*j)];
    sacc[j] = (f32x4){0.f,0.f,0.f,0.f};
  }

  const int gw = blockIdx.x*8 + w;          // 0..4095
  const size_t b0 = (size_t)gw * 8;
  #pragma unroll 1
  for (int rr=0; rr<8; rr+=4){
    f32x4 q[4][4];
    float part[4];
    #pragma unroll
    for (int rq=0;rq<4;++rq){
      const f32x4* qrow = (const f32x4*)(Q0 + (b0 + rr + rq)*NCN);
      float p = 0.f;
      #pragma unroll
      for (int j=0;j<4;++j){
        q[rq][j] = qrow[l + 64*j];
        p += q[rq][j][0]*uu[j][0]; p += q[rq][j][1]*uu[j][1];
        p += q[rq][j][2]*uu[j][2]; p += q[rq][j][3]*uu[j][3];
      }
      part[rq] = p;
    }
    #pragma unroll
    for (int off=32; off; off>>=1){
      #pragma unroll
      for (int rq=0;rq<4;++rq) part[rq] += __shfl_xor(part[rq], off, 64);
    }
    #pragma unroll
    for (int rq=0;rq<4;++rq){
      const float v = alpha / part[rq];
      #pragma unroll
      for (int j=0;j<4;++j){
        sacc[j][0] += q[rq][j][0]*v; sacc[j][1] += q[rq][j][1]*v;
        sacc[j][2] += q[rq][j][2]*v; sacc[j][3] += q[rq][j][3]*v;
      }
    }
  }
  #pragma unroll
  for (int j=0;j<4;++j) *(f32x4*)&Sw[w][4*(l + 64*j)] = sacc[j];
  __syncthreads();
  #pragma unroll
  for (int m=0;m<2;++m){
    int k = t + 512*m;
    S_part[(size_t)blockIdx.x*NCN + k] =
        (((Sw[0][k]+Sw[1][k])+(Sw[2][k]+Sw[3][k])) +
         ((Sw[4][k]+Sw[5][k])+(Sw[6][k]+Sw[7][k])));
  }
}

// ---------------- K4: u = r / colsum(S_part over 512 rows) ----------------
__global__ __launch_bounds__(256) void k4_unew(
    const float* __restrict__ S_part, float* __restrict__ u)
{
  __shared__ float P[256];
  const int t = threadIdx.x;
  const int c = t & 15;
  const int seg = t >> 4;
  const int col = blockIdx.x*16 + c;
  float p = 0.f;
  #pragma unroll 4
  for (int i=0;i<32;++i)
    p += S_part[(size_t)(seg*32 + i)*NCN + col];
  P[seg*16 + c] = p;
  __syncthreads();
  #pragma unroll
  for (int s2=8; s2>0; s2>>=1){
    if (seg < s2) P[seg*16 + c] += P[(seg+s2)*16 + c];
    __syncthreads();
  }
  if (seg == 0) u[col] = (1.0f/1024.0f) / P[c];
}

// ---------------- K5: final pass (512 blocks x 512 threads, 8 rows/wave) -----
__global__ __launch_bounds__(512, 2) void k5_final(
    const float* __restrict__ Q0, const float* __restrict__ u,
    float* __restrict__ softc_part, float* __restrict__ loss_part,
    int* __restrict__ hist_raw, int* __restrict__ hist_clu,
    float* __restrict__ out_ba)
{
  __shared__ __align__(16) float Sw[8][NCN];
  __shared__ float lossw[8];
  const int t = threadIdx.x;
  const int w = t >> 6, l = t & 63;

  f32x4 uu[4], sacc[4];
  #pragma unroll
  for (int j=0;j<4;++j){
    uu[j] = *(const f32x4*)&u[4*(l + 64*j)];
    sacc[j] = (f32x4){0.f,0.f,0.f,0.f};
  }

  const int gw = blockIdx.x*8 + w;          // 0..4095
  const size_t b0 = (size_t)gw * 8;
  float lacc = 0.f;
  #pragma unroll 1
  for (int rr=0; rr<8; ++rr){
    const size_t b = b0 + rr;
    const f32x4* qrow = (const f32x4*)(Q0 + b*NCN);
    f32x4 q4[4], wv4[4];
    float part = 0.f;
    #pragma unroll
    for (int j=0;j<4;++j){
      q4[j] = qrow[l + 64*j];
      wv4[j][0] = uu[j][0]*q4[j][0]; wv4[j][1] = uu[j][1]*q4[j][1];
      wv4[j][2] = uu[j][2]*q4[j][2]; wv4[j][3] = uu[j][3]*q4[j][3];
      part += wv4[j][0]; part += wv4[j][1]; part += wv4[j][2]; part += wv4[j][3];
    }
    #pragma unroll
    for (int off=32; off; off>>=1) part += __shfl_xor(part, off, 64);
    const float inv = 1.0f / part;

    // ascending-k scan, strict compares -> numpy first-index tie-breaking
    float smin = wv4[0][0] * inv; int kmin = 4*l; float qat = q4[0][0];
    float qmax = q4[0][0];        int kmax = 4*l;
    #pragma unroll
    for (int j=0;j<4;++j){
      #pragma unroll
      for (int c=0;c<4;++c){
        if (j==0 && c==0) continue;
        const float qv = q4[j][c];
        const float sv = wv4[j][c] * inv;
        const int k = 4*(l + 64*j) + c;
        if (sv < smin){ smin = sv; kmin = k; qat = qv; }
        if (qv > qmax){ qmax = qv; kmax = k; }
      }
    }
    #pragma unroll
    for (int off=32; off; off>>=1){
      float s2 = __shfl_xor(smin, off, 64);
      int   k2 = __shfl_xor(kmin, off, 64);
      float q2 = __shfl_xor(qat,  off, 64);
      if (s2 < smin || (s2 == smin && k2 < kmin)){ smin=s2; kmin=k2; qat=q2; }
      float m2 = __shfl_xor(qmax, off, 64);
      int   i2 = __shfl_xor(kmax, off, 64);
      if (m2 > qmax || (m2 == qmax && i2 < kmax)){ qmax=m2; kmax=i2; }
    }
    #pragma unroll
    for (int j=0;j<4;++j){
      sacc[j][0] += wv4[j][0]*inv; sacc[j][1] += wv4[j][1]*inv;
      sacc[j][2] += wv4[j][2]*inv; sacc[j][3] += wv4[j][3]*inv;
    }
    if (l == 0){
      out_ba[b] = (float)kmin;
      atomicAdd(&hist_clu[kmin], 1);
      atomicAdd(&hist_raw[kmax], 1);
      lacc += -0.5f * logf(qat);
    }
  }
  #pragma unroll
  for (int j=0;j<4;++j) *(f32x4*)&Sw[w][4*(l + 64*j)] = sacc[j];
  if (l == 0) lossw[w] = lacc;
  __syncthreads();
  #pragma unroll
  for (int m=0;m<2;++m){
    int k = t + 512*m;
    softc_part[(size_t)blockIdx.x*NCN + k] =
        (((Sw[0][k]+Sw[1][k])+(Sw[2][k]+Sw[3][k])) +
         ((Sw[4][k]+Sw[5][k])+(Sw[6][k]+Sw[7][k])));
  }
  if (t == 0)
    loss_part[blockIdx.x] = (((lossw[0]+lossw[1])+(lossw[2]+lossw[3])) +
                             ((lossw[4]+lossw[5])+(lossw[6]+lossw[7])));
}

// ---------------- K6: deterministic combine + output write ----------------
__global__ __launch_bounds__(1024) void k6_fin(
    const float* __restrict__ softc_part, const float* __restrict__ loss_part,
    const int* __restrict__ hist_raw, const int* __restrict__ hist_clu,
    const int* __restrict__ raw_in, const int* __restrict__ clu_in,
    const float* __restrict__ tsoft_in, float* __restrict__ out)
{
  const int k = threadIdx.x;
  float s0=0.f,s1=0.f,s2=0.f,s3=0.f;
  for (int blk=0; blk<512; blk+=4){
    s0 += softc_part[(size_t)(blk+0)*NCN + k];
    s1 += softc_part[(size_t)(blk+1)*NCN + k];
    s2 += softc_part[(size_t)(blk+2)*NCN + k];
    s3 += softc_part[(size_t)(blk+3)*NCN + k];
  }
  const float s = ((s0+s1)+(s2+s3));
  out[1 + BN + k]           = s;
  out[1 + BN + NCN + k]     = (float)(raw_in[k] + hist_raw[k]);
  out[1 + BN + 2*NCN + k]   = (float)(clu_in[k] + hist_clu[k]);
  out[1 + BN + 3*NCN + k]   = tsoft_in[k] + s;
  if (k == 0){
    float ls = 0.f;
    for (int i=0;i<512;++i) ls += loss_part[i];
    out[0] = ls / 32768.0f;
  }
}

extern "C" void kernel_launch(void* const* d_in, const int* in_sizes, int n_in,
                              void* d_out, int out_size, void* d_ws, size_t ws_size,
                              hipStream_t stream) {
  (void)in_sizes; (void)n_in; (void)out_size; (void)ws_size;
  const float* x      = (const float*)d_in[0];
  const float* W1     = (const float*)d_in[1];
  const float* b1     = (const float*)d_in[2];
  const float* W2     = (const float*)d_in[3];
  const float* b2     = (const float*)d_in[4];
  const float* cent   = (const float*)d_in[5];
  const int*   clu_in = (const int*)d_in[6];
  const int*   raw_in = (const int*)d_in[7];
  const float* tsoft  = (const float*)d_in[8];
  float* out = (float*)d_out;

  // ws layout (float units). Lifetime aliasing:
  //  - X-splits (k1-only) overlay Q0 + its tail slack.
  //  - softc_par/loss_par live in the slack behind Q0 (dead before k5).
  //  - fv/cent splits overlay W splits (dead after k1).
  float* ws        = (float*)d_ws;
  float* fv        = ws;                        // 4,194,304 floats
  float* Q0        = ws + 4194304;              // 33,554,432 floats
  u16*   Xh        = (u16*)Q0;                  // 3 x 25,165,824 u16
  u16*   Xm        = Xh + 25165824;
  u16*   Xl        = Xm + 25165824;
  float* softc_par = ws + 37748736;             // 524,288 (slack behind Q0)
  float* loss_par  = softc_par + 524288;        // 512
  float* u         = ws + 41943040;             // 1024
  float* S_part    = u + 1024;                  // 524,288 (512x1024)
  int*   hist_raw  = (int*)(S_part + 524288);   // 1024 ints
  int*   hist_clu  = hist_raw + 1024;           // 1024 ints
  float* wbase     = (float*)(hist_clu + 1024); // union region
  u16* W1Th = (u16*)wbase;
  u16* W1Tm = W1Th + 1572864;
  u16* W1Tl = W1Tm + 1572864;
  u16* W2Th = W1Tl + 1572864;
  u16* W2Tm = W2Th + 262144;
  u16* W2Tl = W2Tm + 262144;
  u16* fvh = (u16*)wbase;
  u16* fvm = fvh + 4194304;
  u16* fvl = fvm + 4194304;
  u16* ch  = fvl + 4194304;
  u16* cm  = ch  + 131072;
  u16* cl  = cm  + 131072;
  float* fvn = wbase + 6488064;                 // 32,768
  float* cn  = fvn + 32768;                     // 1,024
  float* out_ba = out + 1;

  c_split <<<24576, 256, 0, stream>>>(x, Xh, Xm, Xl, 6291456);
  c_tsplit<<<dim3(12, 32), 256, 0, stream>>>(W1, 768, 2048, W1Th, W1Tm, W1Tl);
  c_tsplit<<<dim3(32, 2),  256, 0, stream>>>(W2, 2048, 128, W2Th, W2Tm, W2Tl);
  k0_init<<<1, 1024, 0, stream>>>(u, hist_raw, hist_clu);

  k1_mfma<<<512, 256, 0, stream>>>(Xh, Xm, Xl, W1Th, W1Tm, W1Tl, b1,
                                   W2Th, W2Tm, W2Tl, b2, fv);

  c_split<<<4096, 256, 0, stream>>>(fv,   fvh, fvm, fvl, 1048576);
  c_split<<<128,  256, 0, stream>>>(cent, ch,  cm,  cl,  32768);
  c_norm <<<8192, 256, 0, stream>>>(fv,   fvn);
  c_norm <<<256,  256, 0, stream>>>(cent, cn);

  k2_mfma<<<512, 256, 0, stream>>>(fvh, fvm, fvl, ch, cm, cl, fvn, cn, Q0);

  for (int it = 0; it < 15; ++it){
    const float alpha = (it == 0) ? 1.0f : (1.0f/32768.0f);
    k3_pass<<<512, 512, 0, stream>>>(Q0, u, S_part, alpha);
    k4_unew<<<64, 256, 0, stream>>>(S_part, u);
  }
  k5_final<<<512, 512, 0, stream>>>(Q0, u, softc_par, loss_par,
                                    hist_raw, hist_clu, out_ba);
  k6_fin<<<1, 1024, 0, stream>>>(softc_par, loss_par, hist_raw, hist_clu,
                                 raw_in, clu_in, tsoft, out);
}

// Round 11
// 1266.667 us; speedup vs baseline: 1.5902x; 1.0444x over previous
//
#include <hip/hip_runtime.h>
#include <math.h>

// Problem constants (B, D_IN, H, NZ, NC)
#define BN    32768
#define DIN   768
#define HN    2048
#define NZ    128
#define NCN   1024

typedef __attribute__((ext_vector_type(8))) short s16x8;
typedef __attribute__((ext_vector_type(4))) float f32x4;
typedef unsigned short u16;

#define MFMA16(a,b,c) __builtin_amdgcn_mfma_f32_16x16x32_bf16(a,b,c,0,0,0)

__device__ __forceinline__ u16 bf16_rne(float x){
  unsigned u = __float_as_uint(x);
  unsigned r = (u + 0x7FFFu + ((u >> 16) & 1u)) >> 16;
  return (u16)r;
}
__device__ __forceinline__ float bf16_tof(u16 h){
  return __uint_as_float(((unsigned)h) << 16);
}
__device__ __forceinline__ void split3(float x, u16& h, u16& m, u16& l){
  h = bf16_rne(x);
  float r1 = x - bf16_tof(h);
  m = bf16_rne(r1);
  float r2 = r1 - bf16_tof(m);
  l = bf16_rne(r2);
}

__device__ __forceinline__ void gload16(const void* gsrc, void* lds){
  __builtin_amdgcn_global_load_lds(
      (const __attribute__((address_space(1))) unsigned int*)gsrc,
      (__attribute__((address_space(3))) unsigned int*)lds, 16, 0, 0);
}

// ---------------- K0: init (u=1, histograms=0) ----------------
__global__ __launch_bounds__(1024) void k0_init(float* u, int* hraw, int* hclu){
  const int k = threadIdx.x;
  u[k] = 1.0f;
  hraw[k] = 0;
  hclu[k] = 0;
}

// ---------------- Convert: elementwise 3-way bf16 split ----------------
__global__ __launch_bounds__(256) void c_split(
    const float* __restrict__ in, u16* __restrict__ oh, u16* __restrict__ om,
    u16* __restrict__ ol, int n4)
{
  const int i = blockIdx.x*256 + threadIdx.x;
  if (i >= n4) return;
  const f32x4 v = *(const f32x4*)&in[(size_t)i*4];
  ushort4 h4, m4, l4;
  split3(v[0], h4.x, m4.x, l4.x);
  split3(v[1], h4.y, m4.y, l4.y);
  split3(v[2], h4.z, m4.z, l4.z);
  split3(v[3], h4.w, m4.w, l4.w);
  *(ushort4*)&oh[(size_t)i*4] = h4;
  *(ushort4*)&om[(size_t)i*4] = m4;
  *(ushort4*)&ol[(size_t)i*4] = l4;
}

// ---------------- Convert: transpose + 3-way bf16 split ----------------
__global__ __launch_bounds__(256) void c_tsplit(
    const float* __restrict__ in, int R, int C,
    u16* __restrict__ oh, u16* __restrict__ om, u16* __restrict__ ol)
{
  __shared__ float L[64][65];
  const int t = threadIdx.x;
  const int bi = blockIdx.x, bj = blockIdx.y;
  #pragma unroll
  for (int m=0;m<4;++m){
    int flat = t + 256*m;
    int r = flat >> 4, c4 = (flat & 15) << 2;
    const float4 v = *(const float4*)&in[(size_t)(bi*64 + r)*C + bj*64 + c4];
    L[r][c4+0] = v.x; L[r][c4+1] = v.y; L[r][c4+2] = v.z; L[r][c4+3] = v.w;
  }
  __syncthreads();
  #pragma unroll
  for (int m=0;m<4;++m){
    int flat = t + 256*m;
    int oc = flat >> 4, k4 = (flat & 15) << 2;
    ushort4 h4, m4, l4;
    split3(L[k4+0][oc], h4.x, m4.x, l4.x);
    split3(L[k4+1][oc], h4.y, m4.y, l4.y);
    split3(L[k4+2][oc], h4.z, m4.z, l4.z);
    split3(L[k4+3][oc], h4.w, m4.w, l4.w);
    size_t off = (size_t)(bj*64 + oc)*R + bi*64 + k4;
    *(ushort4*)&oh[off] = h4;
    *(ushort4*)&om[off] = m4;
    *(ushort4*)&ol[off] = l4;
  }
}

// ---------------- Convert: row sum-of-squares, rows of 128 ----------------
__global__ __launch_bounds__(256) void c_norm(
    const float* __restrict__ in, float* __restrict__ out)
{
  const int w = threadIdx.x >> 6, l = threadIdx.x & 63;
  const int row = blockIdx.x*4 + w;
  const float2 v = *(const float2*)&in[(size_t)row*128 + l*2];
  float s = v.x*v.x + v.y*v.y;
  #pragma unroll
  for (int off=32; off; off>>=1) s += __shfl_xor(s, off, 64);
  if (l == 0) out[row] = s;
}

// ---------------- K1: fused MFMA backbone fv = relu(X@W1+b1)@W2 + b2 ----------------
// R6 structure (known-good 674us, no spills) + bijective XCD swizzle.
__global__ __launch_bounds__(256, 2) void k1_mfma(
    const u16* __restrict__ Xh, const u16* __restrict__ Xm, const u16* __restrict__ Xl,
    const u16* __restrict__ W1h, const u16* __restrict__ W1m, const u16* __restrict__ W1l,
    const float* __restrict__ b1,
    const u16* __restrict__ W2h, const u16* __restrict__ W2m, const u16* __restrict__ W2l,
    const float* __restrict__ b2, float* __restrict__ fv)
{
  __shared__ __align__(16) unsigned char sm[73728];
  unsigned char* xsr = sm;          // 3 * 8192
  unsigned char* wsr = sm + 24576;  // 3 * 16384

  const int t  = threadIdx.x;
  const int l  = t & 63;
  const int wn = t >> 6;
  const int g  = (l >> 4) & 3;
  const int lr = l & 15;
  const int bid = blockIdx.x;
  const int swz = (bid & 7)*64 + (bid >> 3);   // 512 blocks, bijective
  const int row0 = swz * 64;

  f32x4 fvacc[4][2];
  #pragma unroll
  for (int mf=0;mf<4;++mf){
    fvacc[mf][0] = (f32x4){0.f,0.f,0.f,0.f};
    fvacc[mf][1] = (f32x4){0.f,0.f,0.f,0.f};
  }

  #pragma unroll 1
  for (int nc = 0; nc < 16; ++nc){
    f32x4 a1acc[4][2];
    #pragma unroll
    for (int mf=0;mf<4;++mf){
      a1acc[mf][0] = (f32x4){0.f,0.f,0.f,0.f};
      a1acc[mf][1] = (f32x4){0.f,0.f,0.f,0.f};
    }

    // Phase A: A1 = X @ W1[:, nc*128 : +128]
    #pragma unroll 1
    for (int ks = 0; ks < 12; ++ks){
      #pragma unroll
      for (int i=0;i<6;++i){
        const int ci = wn*6 + i;
        const int s  = ci >> 3;
        const int rb = ci & 7;
        const int xr = rb*8 + (l >> 3);
        const int q  = l & 7;
        const u16* Xp = (s==0) ? Xh : ((s==1) ? Xm : Xl);
        const u16* src = Xp + (size_t)(row0 + xr)*768 + ks*64 + ((q ^ (xr & 7)) << 3);
        gload16(src, xsr + s*8192 + rb*1024);
      }
      #pragma unroll
      for (int i=0;i<12;++i){
        const int ci = wn*12 + i;
        const int s  = ci >> 4;
        const int rb = ci & 15;
        const int rloc = rb*8 + (l >> 3);
        const int q  = l & 7;
        const u16* Wp = (s==0) ? W1h : ((s==1) ? W1m : W1l);
        const u16* src = Wp + (size_t)(nc*128 + rloc)*768 + ks*64 + ((q ^ (rloc & 7)) << 3);
        gload16(src, wsr + s*16384 + rb*1024);
      }
      __syncthreads();

      #pragma unroll
      for (int kk=0;kk<2;++kk){
        s16x8 Bf[3][2], Af[3][4];
        #pragma unroll
        for (int s=0;s<3;++s){
          #pragma unroll
          for (int nf=0;nf<2;++nf){
            const int br = wn*32 + nf*16 + lr;
            Bf[s][nf] = *(const s16x8*)(wsr + s*16384 + br*128 + ((16*(g + 4*kk)) ^ ((br & 7) << 4)));
          }
          #pragma unroll
          for (int mf=0;mf<4;++mf){
            const int ar = mf*16 + lr;
            Af[s][mf] = *(const s16x8*)(xsr + s*8192 + ar*128 + ((16*(g + 4*kk)) ^ ((ar & 7) << 4)));
          }
        }
        #pragma unroll
        for (int mf=0;mf<4;++mf){
          #pragma unroll
          for (int nf=0;nf<2;++nf){
            f32x4 acc = a1acc[mf][nf];
            acc = MFMA16(Af[0][mf], Bf[0][nf], acc);
            acc = MFMA16(Af[0][mf], Bf[1][nf], acc);
            acc = MFMA16(Af[1][mf], Bf[0][nf], acc);
            acc = MFMA16(Af[1][mf], Bf[1][nf], acc);
            acc = MFMA16(Af[0][mf], Bf[2][nf], acc);
            acc = MFMA16(Af[2][mf], Bf[0][nf], acc);
            a1acc[mf][nf] = acc;
          }
        }
      }
      __syncthreads();
    }

    // Phase B: fv += relu(A1+b1) @ W2[nc chunk]
    const float b1v0 = b1[nc*128 + wn*32 + lr];
    const float b1v1 = b1[nc*128 + wn*32 + 16 + lr];

    #pragma unroll
    for (int half=0; half<2; ++half){
      if ((wn >> 1) == half){
        #pragma unroll
        for (int mf=0;mf<4;++mf){
          #pragma unroll
          for (int nf=0;nf<2;++nf){
            const int klocal = (wn & 1)*32 + nf*16 + lr;
            #pragma unroll
            for (int r=0;r<4;++r){
              float vv = a1acc[mf][nf][r] + ((nf==0) ? b1v0 : b1v1);
              vv = vv > 0.f ? vv : 0.f;
              u16 sh, sm2, sl;
              split3(vv, sh, sm2, sl);
              const int ar = mf*16 + g*4 + r;
              const int bo = ar*128 + ((2*klocal) ^ ((ar & 7) << 4));
              *(u16*)(xsr + bo)         = sh;
              *(u16*)(xsr + 8192 + bo)  = sm2;
              *(u16*)(xsr + 16384 + bo) = sl;
            }
          }
        }
      }
      #pragma unroll
      for (int i=0;i<12;++i){
        const int ci = wn*12 + i;
        const int s  = ci >> 4;
        const int rb = ci & 15;
        const int rloc = rb*8 + (l >> 3);
        const int q  = l & 7;
        const u16* Wp = (s==0) ? W2h : ((s==1) ? W2m : W2l);
        const u16* src = Wp + (size_t)rloc*2048 + nc*128 + half*64 + ((q ^ (rloc & 7)) << 3);
        gload16(src, wsr + s*16384 + rb*1024);
      }
      __syncthreads();

      #pragma unroll
      for (int kk=0;kk<2;++kk){
        s16x8 Bf[3][2], Af[3][4];
        #pragma unroll
        for (int s=0;s<3;++s){
          #pragma unroll
          for (int nf=0;nf<2;++nf){
            const int br = wn*32 + nf*16 + lr;
            Bf[s][nf] = *(const s16x8*)(wsr + s*16384 + br*128 + ((16*(g + 4*kk)) ^ ((br & 7) << 4)));
          }
          #pragma unroll
          for (int mf=0;mf<4;++mf){
            const int ar = mf*16 + lr;
            Af[s][mf] = *(const s16x8*)(xsr + s*8192 + ar*128 + ((16*(g + 4*kk)) ^ ((ar & 7) << 4)));
          }
        }
        #pragma unroll
        for (int mf=0;mf<4;++mf){
          #pragma unroll
          for (int nf=0;nf<2;++nf){
            f32x4 acc = fvacc[mf][nf];
            acc = MFMA16(Af[0][mf], Bf[0][nf], acc);
            acc = MFMA16(Af[0][mf], Bf[1][nf], acc);
            acc = MFMA16(Af[1][mf], Bf[0][nf], acc);
            acc = MFMA16(Af[1][mf], Bf[1][nf], acc);
            acc = MFMA16(Af[0][mf], Bf[2][nf], acc);
            acc = MFMA16(Af[2][mf], Bf[0][nf], acc);
            fvacc[mf][nf] = acc;
          }
        }
      }
      __syncthreads();
    }
  }

  const float b2v0 = b2[wn*32 + lr];
  const float b2v1 = b2[wn*32 + 16 + lr];
  #pragma unroll
  for (int mf=0;mf<4;++mf){
    #pragma unroll
    for (int nf=0;nf<2;++nf){
      #pragma unroll
      for (int r=0;r<4;++r){
        const int frow = row0 + mf*16 + g*4 + r;
        const int col  = wn*32 + nf*16 + lr;
        fv[(size_t)frow*NZ + col] = fvacc[mf][nf][r] + ((nf==0) ? b2v0 : b2v1);
      }
    }
  }
}

// ---------------- K2: MFMA cdist -> Q0 = exp(-2*dist), row-major [BN][NCN] -------
__global__ __launch_bounds__(256, 2) void k2_mfma(
    const u16* __restrict__ fvh, const u16* __restrict__ fvm, const u16* __restrict__ fvl,
    const u16* __restrict__ ch,  const u16* __restrict__ cm,  const u16* __restrict__ cl,
    const float* __restrict__ fvn, const float* __restrict__ cn,
    float* __restrict__ Q0)
{
  __shared__ __align__(16) unsigned char bs[49152];
  __shared__ float cnl[NCN];
  const int t  = threadIdx.x;
  const int l  = t & 63;
  const int wn = t >> 6;
  const int g  = (l >> 4) & 3;
  const int lr = l & 15;
  const int bid = blockIdx.x;
  const int swz = (bid & 7)*64 + (bid >> 3);
  const int row0 = swz * 64;
  const int arow = row0 + wn*16 + lr;

  s16x8 Af[3][4];
  #pragma unroll
  for (int kk=0;kk<4;++kk){
    const size_t ao = (size_t)arow*128 + kk*32 + g*8;
    Af[0][kk] = *(const s16x8*)&fvh[ao];
    Af[1][kk] = *(const s16x8*)&fvm[ao];
    Af[2][kk] = *(const s16x8*)&fvl[ao];
  }
  #pragma unroll
  for (int m=0;m<4;++m) cnl[t + 256*m] = cn[t + 256*m];
  const f32x4 fvnv = *(const f32x4*)&fvn[row0 + wn*16 + g*4];

  #pragma unroll 1
  for (int cc = 0; cc < NCN; cc += 64){
    #pragma unroll
    for (int i=0;i<12;++i){
      const int ci = wn*12 + i;
      const int s  = ci >> 4;
      const int rb = ci & 15;
      const int crow = rb*4 + (l >> 4);
      const int q  = l & 15;
      const u16* Cp = (s==0) ? ch : ((s==1) ? cm : cl);
      const u16* src = Cp + (size_t)(cc + crow)*128 + ((q ^ (crow & 15)) << 3);
      gload16(src, bs + s*16384 + rb*1024);
    }
    __syncthreads();

    f32x4 acc[4];
    #pragma unroll
    for (int nf=0;nf<4;++nf) acc[nf] = (f32x4){0.f,0.f,0.f,0.f};

    #pragma unroll
    for (int kk=0;kk<4;++kk){
      s16x8 Bq[3][4];
      #pragma unroll
      for (int nf=0;nf<4;++nf){
        const int br = nf*16 + lr;
        const int base = br*256 + (((g + 4*kk) ^ (br & 15)) << 4);
        Bq[0][nf] = *(const s16x8*)(bs + base);
        Bq[1][nf] = *(const s16x8*)(bs + 16384 + base);
        Bq[2][nf] = *(const s16x8*)(bs + 32768 + base);
      }
      #pragma unroll
      for (int nf=0;nf<4;++nf){
        f32x4 a = acc[nf];
        a = MFMA16(Af[0][kk], Bq[0][nf], a);
        a = MFMA16(Af[0][kk], Bq[1][nf], a);
        a = MFMA16(Af[1][kk], Bq[0][nf], a);
        a = MFMA16(Af[1][kk], Bq[1][nf], a);
        a = MFMA16(Af[0][kk], Bq[2][nf], a);
        a = MFMA16(Af[2][kk], Bq[0][nf], a);
        acc[nf] = a;
      }
    }

    #pragma unroll
    for (int nf=0;nf<4;++nf){
      const int n = cc + nf*16 + lr;
      const float cv = cnl[n];
      #pragma unroll
      for (int r=0;r<4;++r){
        float sq = fvnv[r] + cv - 2.0f*acc[nf][r];
        sq = sq > 1e-12f ? sq : 1e-12f;
        const float d = sqrtf(sq);
        Q0[(size_t)(row0 + wn*16 + g*4 + r)*NCN + n] = expf(-2.0f*d);
      }
    }
    __syncthreads();
  }
}

// ---------------- K3: one fused sinkhorn pass (R6 config) ----------------
__global__ __launch_bounds__(256, 2) void k3_pass(
    const float* __restrict__ Q0, const float* __restrict__ u,
    float* __restrict__ S_part, float alpha)
{
  __shared__ __align__(16) float Sw[4][NCN];
  const int t = threadIdx.x;
  const int w = t >> 6, l = t & 63;

  f32x4 uu[4], sacc[4];
  #pragma unroll
  for (int j=0;j<4;++j){
    uu[j] = *(const f32x4*)&u[4*(l + 64*j)];
    sacc[j] = (f32x4){0.f,0.f,0.f,0.f};
  }

  const int gw = blockIdx.x*4 + w;          // 0..2047
  const size_t b0 = (size_t)gw * 16;
  #pragma unroll 1
  for (int rr=0; rr<16; rr+=4){
    f32x4 q[4][4];
    float part[4];
    #pragma unroll
    for (int rq=0;rq<4;++rq){
      const f32x4* qrow = (const f32x4*)(Q0 + (b0 + rr + rq)*NCN);
      float p = 0.f;
      #pragma unroll
      for (int j=0;j<4;++j){
        q[rq][j] = qrow[l + 64*j];
        p += q[rq][j][0]*uu[j][0]; p += q[rq][j][1]*uu[j][1];
        p += q[rq][j][2]*uu[j][2]; p += q[rq][j][3]*uu[j][3];
      }
      part[rq] = p;
    }
    #pragma unroll
    for (int off=32; off; off>>=1){
      #pragma unroll
      for (int rq=0;rq<4;++rq) part[rq] += __shfl_xor(part[rq], off, 64);
    }
    #pragma unroll
    for (int rq=0;rq<4;++rq){
      const float v = alpha / part[rq];
      #pragma unroll
      for (int j=0;j<4;++j){
        sacc[j][0] += q[rq][j][0]*v; sacc[j][1] += q[rq][j][1]*v;
        sacc[j][2] += q[rq][j][2]*v; sacc[j][3] += q[rq][j][3]*v;
      }
    }
  }
  #pragma unroll
  for (int j=0;j<4;++j) *(f32x4*)&Sw[w][4*(l + 64*j)] = sacc[j];
  __syncthreads();
  #pragma unroll
  for (int m=0;m<4;++m){
    int k = t + 256*m;
    S_part[(size_t)blockIdx.x*NCN + k] = ((Sw[0][k]+Sw[1][k])+(Sw[2][k]+Sw[3][k]));
  }
}

// ---------------- K4: u = r / colsum(S_part over 512 rows) ----------------
__global__ __launch_bounds__(256) void k4_unew(
    const float* __restrict__ S_part, float* __restrict__ u)
{
  __shared__ float P[256];
  const int t = threadIdx.x;
  const int c = t & 15;
  const int seg = t >> 4;
  const int col = blockIdx.x*16 + c;
  float p = 0.f;
  #pragma unroll 4
  for (int i=0;i<32;++i)
    p += S_part[(size_t)(seg*32 + i)*NCN + col];
  P[seg*16 + c] = p;
  __syncthreads();
  #pragma unroll
  for (int s2=8; s2>0; s2>>=1){
    if (seg < s2) P[seg*16 + c] += P[(seg+s2)*16 + c];
    __syncthreads();
  }
  if (seg == 0) u[col] = (1.0f/1024.0f) / P[c];
}

// ---------------- K5: final pass (512 blocks, 16 rows/wave) ----------------
__global__ __launch_bounds__(256, 2) void k5_final(
    const float* __restrict__ Q0, const float* __restrict__ u,
    float* __restrict__ softc_part, float* __restrict__ loss_part,
    int* __restrict__ hist_raw, int* __restrict__ hist_clu,
    float* __restrict__ out_ba)
{
  __shared__ __align__(16) float Sw[4][NCN];
  __shared__ float lossw[4];
  const int t = threadIdx.x;
  const int w = t >> 6, l = t & 63;

  f32x4 uu[4], sacc[4];
  #pragma unroll
  for (int j=0;j<4;++j){
    uu[j] = *(const f32x4*)&u[4*(l + 64*j)];
    sacc[j] = (f32x4){0.f,0.f,0.f,0.f};
  }

  const int gw = blockIdx.x*4 + w;          // 0..2047
  const size_t b0 = (size_t)gw * 16;
  float lacc = 0.f;
  #pragma unroll 1
  for (int rr=0; rr<16; ++rr){
    const size_t b = b0 + rr;
    const f32x4* qrow = (const f32x4*)(Q0 + b*NCN);
    f32x4 q4[4], wv4[4];
    float part = 0.f;
    #pragma unroll
    for (int j=0;j<4;++j){
      q4[j] = qrow[l + 64*j];
      wv4[j][0] = uu[j][0]*q4[j][0]; wv4[j][1] = uu[j][1]*q4[j][1];
      wv4[j][2] = uu[j][2]*q4[j][2]; wv4[j][3] = uu[j][3]*q4[j][3];
      part += wv4[j][0]; part += wv4[j][1]; part += wv4[j][2]; part += wv4[j][3];
    }
    #pragma unroll
    for (int off=32; off; off>>=1) part += __shfl_xor(part, off, 64);
    const float inv = 1.0f / part;

    float smin = wv4[0][0] * inv; int kmin = 4*l; float qat = q4[0][0];
    float qmax = q4[0][0];        int kmax = 4*l;
    #pragma unroll
    for (int j=0;j<4;++j){
      #pragma unroll
      for (int c=0;c<4;++c){
        if (j==0 && c==0) continue;
        const float qv = q4[j][c];
        const float sv = wv4[j][c] * inv;
        const int k = 4*(l + 64*j) + c;
        if (sv < smin){ smin = sv; kmin = k; qat = qv; }
        if (qv > qmax){ qmax = qv; kmax = k; }
      }
    }
    #pragma unroll
    for (int off=32; off; off>>=1){
      float s2 = __shfl_xor(smin, off, 64);
      int   k2 = __shfl_xor(kmin, off, 64);
      float q2 = __shfl_xor(qat,  off, 64);
      if (s2 < smin || (s2 == smin && k2 < kmin)){ smin=s2; kmin=k2; qat=q2; }
      float m2 = __shfl_xor(qmax, off, 64);
      int   i2 = __shfl_xor(kmax, off, 64);
      if (m2 > qmax || (m2 == qmax && i2 < kmax)){ qmax=m2; kmax=i2; }
    }
    #pragma unroll
    for (int j=0;j<4;++j){
      sacc[j][0] += wv4[j][0]*inv; sacc[j][1] += wv4[j][1]*inv;
      sacc[j][2] += wv4[j][2]*inv; sacc[j][3] += wv4[j][3]*inv;
    }
    if (l == 0){
      out_ba[b] = (float)kmin;
      atomicAdd(&hist_clu[kmin], 1);
      atomicAdd(&hist_raw[kmax], 1);
      lacc += -0.5f * logf(qat);
    }
  }
  #pragma unroll
  for (int j=0;j<4;++j) *(f32x4*)&Sw[w][4*(l + 64*j)] = sacc[j];
  if (l == 0) lossw[w] = lacc;
  __syncthreads();
  #pragma unroll
  for (int m=0;m<4;++m){
    int k = t + 256*m;
    softc_part[(size_t)blockIdx.x*NCN + k] = ((Sw[0][k]+Sw[1][k])+(Sw[2][k]+Sw[3][k]));
  }
  if (t == 0) loss_part[blockIdx.x] = ((lossw[0]+lossw[1])+(lossw[2]+lossw[3]));
}

// ---------------- K6: deterministic combine + output write (parallel) ----------
// Blocks 0..7: 128 cols each (per-column arithmetic byte-identical to the
// single-block version). Block 8: loss tree.
__global__ __launch_bounds__(128) void k6_fin(
    const float* __restrict__ softc_part, const float* __restrict__ loss_part,
    const int* __restrict__ hist_raw, const int* __restrict__ hist_clu,
    const int* __restrict__ raw_in, const int* __restrict__ clu_in,
    const float* __restrict__ tsoft_in, float* __restrict__ out)
{
  const int bid = blockIdx.x;
  const int t = threadIdx.x;
  if (bid < 8){
    const int k = bid*128 + t;
    float s0=0.f,s1=0.f,s2=0.f,s3=0.f;
    for (int blk=0; blk<512; blk+=4){
      s0 += softc_part[(size_t)(blk+0)*NCN + k];
      s1 += softc_part[(size_t)(blk+1)*NCN + k];
      s2 += softc_part[(size_t)(blk+2)*NCN + k];
      s3 += softc_part[(size_t)(blk+3)*NCN + k];
    }
    const float s = ((s0+s1)+(s2+s3));
    out[1 + BN + k]           = s;
    out[1 + BN + NCN + k]     = (float)(raw_in[k] + hist_raw[k]);
    out[1 + BN + 2*NCN + k]   = (float)(clu_in[k] + hist_clu[k]);
    out[1 + BN + 3*NCN + k]   = tsoft_in[k] + s;
  } else {
    if (t == 0){
      float ls = 0.f;
      for (int i=0;i<512;++i) ls += loss_part[i];
      out[0] = ls / 32768.0f;
    }
  }
}

extern "C" void kernel_launch(void* const* d_in, const int* in_sizes, int n_in,
                              void* d_out, int out_size, void* d_ws, size_t ws_size,
                              hipStream_t stream) {
  (void)in_sizes; (void)n_in; (void)out_size; (void)ws_size;
  const float* x      = (const float*)d_in[0];
  const float* W1     = (const float*)d_in[1];
  const float* b1     = (const float*)d_in[2];
  const float* W2     = (const float*)d_in[3];
  const float* b2     = (const float*)d_in[4];
  const float* cent   = (const float*)d_in[5];
  const int*   clu_in = (const int*)d_in[6];
  const int*   raw_in = (const int*)d_in[7];
  const float* tsoft  = (const float*)d_in[8];
  float* out = (float*)d_out;

  // ws layout (float units). Lifetime aliasing:
  //  - X-splits (k1-only) overlay Q0 + its tail slack.
  //  - softc_par/loss_par live in the slack behind Q0 (dead before k5).
  //  - fv/cent splits overlay W splits (dead after k1).
  float* ws        = (float*)d_ws;
  float* fv        = ws;                        // 4,194,304 floats
  float* Q0        = ws + 4194304;              // 33,554,432 floats
  u16*   Xh        = (u16*)Q0;                  // 3 x 25,165,824 u16
  u16*   Xm        = Xh + 25165824;
  u16*   Xl        = Xm + 25165824;
  float* softc_par = ws + 37748736;             // 524,288 (slack behind Q0)
  float* loss_par  = softc_par + 524288;        // 512
  float* u         = ws + 41943040;             // 1024
  float* S_part    = u + 1024;                  // 524,288 (512x1024)
  int*   hist_raw  = (int*)(S_part + 524288);   // 1024 ints
  int*   hist_clu  = hist_raw + 1024;           // 1024 ints
  float* wbase     = (float*)(hist_clu + 1024); // union region
  u16* W1Th = (u16*)wbase;
  u16* W1Tm = W1Th + 1572864;
  u16* W1Tl = W1Tm + 1572864;
  u16* W2Th = W1Tl + 1572864;
  u16* W2Tm = W2Th + 262144;
  u16* W2Tl = W2Tm + 262144;
  u16* fvh = (u16*)wbase;
  u16* fvm = fvh + 4194304;
  u16* fvl = fvm + 4194304;
  u16* ch  = fvl + 4194304;
  u16* cm  = ch  + 131072;
  u16* cl  = cm  + 131072;
  float* fvn = wbase + 6488064;                 // 32,768
  float* cn  = fvn + 32768;                     // 1,024
  float* out_ba = out + 1;

  c_split <<<24576, 256, 0, stream>>>(x, Xh, Xm, Xl, 6291456);
  c_tsplit<<<dim3(12, 32), 256, 0, stream>>>(W1, 768, 2048, W1Th, W1Tm, W1Tl);
  c_tsplit<<<dim3(32, 2),  256, 0, stream>>>(W2, 2048, 128, W2Th, W2Tm, W2Tl);
  k0_init<<<1, 1024, 0, stream>>>(u, hist_raw, hist_clu);

  k1_mfma<<<512, 256, 0, stream>>>(Xh, Xm, Xl, W1Th, W1Tm, W1Tl, b1,
                                   W2Th, W2Tm, W2Tl, b2, fv);

  c_split<<<4096, 256, 0, stream>>>(fv,   fvh, fvm, fvl, 1048576);
  c_split<<<128,  256, 0, stream>>>(cent, ch,  cm,  cl,  32768);
  c_norm <<<8192, 256, 0, stream>>>(fv,   fvn);
  c_norm <<<256,  256, 0, stream>>>(cent, cn);

  k2_mfma<<<512, 256, 0, stream>>>(fvh, fvm, fvl, ch, cm, cl, fvn, cn, Q0);

  for (int it = 0; it < 15; ++it){
    const float alpha = (it == 0) ? 1.0f : (1.0f/32768.0f);
    k3_pass<<<512, 256, 0, stream>>>(Q0, u, S_part, alpha);
    k4_unew<<<64, 256, 0, stream>>>(S_part, u);
  }
  k5_final<<<512, 256, 0, stream>>>(Q0, u, softc_par, loss_par,
                                    hist_raw, hist_clu, out_ba);
  k6_fin<<<9, 128, 0, stream>>>(softc_par, loss_par, hist_raw, hist_clu,
                                raw_in, clu_in, tsoft, out);
}